// Round 1
// baseline (50283.932 us; speedup 1.0000x reference)
//
#include <hip/hip_runtime.h>
#include <math.h>

#define HH 256
#define FIN 6
#define TT 4096
#define BB 32
#define TH 0.05f

__device__ __forceinline__ float hswish(float v) {
    float c = fminf(fmaxf(v + 3.0f, 0.0f), 6.0f);
    return v * c * (1.0f / 6.0f);
}
__device__ __forceinline__ float fexp2(float x) { return __builtin_amdgcn_exp2f(x); }
__device__ __forceinline__ float frcp(float x)  { return __builtin_amdgcn_rcpf(x); }
__device__ __forceinline__ float sigm(float x)  { return frcp(1.0f + fexp2(-1.44269504f * x)); }
__device__ __forceinline__ float tanhf_fast(float x) {
    float ax = fabsf(x);
    float e = fexp2(2.88539008f * ax);           // exp(2|x|)
    float t = 1.0f - 2.0f * frcp(e + 1.0f);      // tanh(|x|)
    return copysignf(t, x);
}

// Kernel 1: feats (B,T,6) into ws, conv skip path into d_out.
__global__ __launch_bounds__(256) void k_prep(
        const float* __restrict__ x, const float* __restrict__ Wc1,
        const float* __restrict__ Wc2, float* __restrict__ feats,
        float* __restrict__ out) {
    int idx = blockIdx.x * 256 + threadIdx.x;   // b*T + t
    if (idx >= BB * TT) return;
    int b = idx >> 12;              // /4096
    int t = idx & (TT - 1);
    const float* xb = x + (size_t)b * TT * 2;
    float i0 = xb[t * 2 + 0], q0 = xb[t * 2 + 1];
    float ip = (t > 0) ? xb[(t - 1) * 2 + 0] : 0.0f;
    float qp = (t > 0) ? xb[(t - 1) * 2 + 1] : 0.0f;
    float amp2 = i0 * i0 + q0 * q0;
    float amp  = sqrtf(fmaxf(amp2, 1e-12f));
    float amp3 = amp * amp2;
    float* f = feats + (size_t)idx * 6;
    f[0] = i0; f[1] = q0; f[2] = amp; f[3] = amp3; f[4] = ip; f[5] = qp;

    // dilated conv (kernel 3, dilation 16, pad 16): taps at t-16, t, t+16
    float c1[3];
#pragma unroll
    for (int m = 0; m < 3; m++) {
        float acc = 0.0f;
#pragma unroll
        for (int k = 0; k < 3; k++) {
            int tt = t + (k - 1) * 16;
            if (tt >= 0 && tt < TT) {
                acc += Wc1[m * 6 + 0 * 3 + k] * xb[tt * 2 + 0];
                acc += Wc1[m * 6 + 1 * 3 + k] * xb[tt * 2 + 1];
            }
        }
        c1[m] = hswish(acc);
    }
#pragma unroll
    for (int o = 0; o < 2; o++) {
        float acc = Wc2[o * 3 + 0] * c1[0] + Wc2[o * 3 + 1] * c1[1] + Wc2[o * 3 + 2] * c1[2];
        out[(size_t)idx * 2 + o] = hswish(acc);
    }
}

// Kernel 2: persistent-weight delta-GRU. One block per batch, 768 threads.
// Thread tid owns row tid of Wh (256 fp32 in registers) and row tid of Wx.
__global__ __launch_bounds__(768, 1) void k_gru(
        const float* __restrict__ feats, const float* __restrict__ Wx,
        const float* __restrict__ Wh, const float* __restrict__ Wo,
        float* __restrict__ out) {
    __shared__ float s_dh[HH];
    __shared__ float s_dx[FIN];
    __shared__ float s_mac[768];
    __shared__ float s_dmnh[HH];
    __shared__ float s_part[4][2];
    __shared__ float s_skip[TT * 2];   // 32 KB: conv skip for this batch

    const int tid = threadIdx.x;
    const int b = blockIdx.x;
    const size_t outbase = (size_t)b * TT * 2;

    // preload skip (written by k_prep into d_out)
    for (int i = tid; i < TT * 2; i += 768) s_skip[i] = out[outbase + i];

    // persistent weights
    float4 w4[64];
    {
        const float4* wr = (const float4*)(Wh + (size_t)tid * HH);
#pragma unroll
        for (int k = 0; k < 64; k++) w4[k] = wr[k];
    }
    float wx[FIN];
#pragma unroll
    for (int f = 0; f < FIN; f++) wx[f] = Wx[tid * FIN + f];

    float h = 0.0f, hp = 0.0f, wo0 = 0.0f, wo1 = 0.0f;
    if (tid < HH) { wo0 = Wo[tid]; wo1 = Wo[HH + tid]; }
    float dm = 0.0f, dmnh = 0.0f;
    float xp = 0.0f, curf = 0.0f, nxtf = 0.0f;
    const float* fb = feats + (size_t)b * TT * 6;
    if (tid >= 256 && tid < 256 + FIN) curf = fb[tid - 256];
    __syncthreads();

    for (int t = 0; t < TT; t++) {
        // ---- phase A: deltas + previous step's output store ----
        if (tid < HH) {
            float dh = h - hp;
            bool keep = fabsf(dh) >= TH;
            s_dh[tid] = keep ? dh : 0.0f;
            if (keep) hp = h;
        } else if (tid < 256 + FIN) {
            int f = tid - 256;
            float dx = curf - xp;
            bool keep = fabsf(dx) >= TH;
            s_dx[f] = keep ? dx : 0.0f;
            if (keep) xp = curf;
            nxtf = (t + 1 < TT) ? fb[(size_t)(t + 1) * 6 + f] : 0.0f;  // prefetch
        } else if (tid < 264) {
            if (t > 0) {
                int c = tid - 262;
                float v = s_part[0][c] + s_part[1][c] + s_part[2][c] + s_part[3][c]
                        + s_skip[(t - 1) * 2 + c];
                out[outbase + (size_t)(t - 1) * 2 + c] = v;
            }
        }
        __syncthreads();

        // ---- phase B: mac_h (register dot vs LDS-broadcast dh) + mac_x ----
        float a0 = 0.0f, a1 = 0.0f, a2 = 0.0f, a3 = 0.0f;
        const float4* d4 = (const float4*)s_dh;
#pragma unroll
        for (int k = 0; k < 64; k++) {
            float4 d = d4[k];
            a0 = fmaf(d.x, w4[k].x, a0);
            a1 = fmaf(d.y, w4[k].y, a1);
            a2 = fmaf(d.z, w4[k].z, a2);
            a3 = fmaf(d.w, w4[k].w, a3);
        }
        float mach = (a0 + a1) + (a2 + a3);
        float macx = dm;
#pragma unroll
        for (int f = 0; f < FIN; f++) macx = fmaf(s_dx[f], wx[f], macx);
        if (tid < 512) {
            dm = macx + mach;            // dm_r / dm_z
        } else {
            dm = macx;                   // dm_n (no mac_h term)
            dmnh += mach;                // dm_nh accumulator (owned)
            s_dmnh[tid - 512] = dmnh;
        }
        s_mac[tid] = dm;
        __syncthreads();

        // ---- phase C: gates + h update + output partials ----
        if (tid < HH) {
            float r = sigm(s_mac[tid]);
            float z = sigm(s_mac[HH + tid]);
            float nn = tanhf_fast(s_mac[2 * HH + tid] + r * s_dmnh[tid]);
            h = (1.0f - z) * nn + z * h;
            float p0 = h * wo0, p1 = h * wo1;
#pragma unroll
            for (int s = 32; s >= 1; s >>= 1) {
                p0 += __shfl_down(p0, s, 64);
                p1 += __shfl_down(p1, s, 64);
            }
            if ((tid & 63) == 0) { int w = tid >> 6; s_part[w][0] = p0; s_part[w][1] = p1; }
        } else if (tid < 256 + FIN) {
            curf = nxtf;
        }
        __syncthreads();
    }
    // flush final timestep's output
    if (tid < 2) {
        float v = s_part[0][tid] + s_part[1][tid] + s_part[2][tid] + s_part[3][tid]
                + s_skip[(TT - 1) * 2 + tid];
        out[outbase + (size_t)(TT - 1) * 2 + tid] = v;
    }
}

extern "C" void kernel_launch(void* const* d_in, const int* in_sizes, int n_in,
                              void* d_out, int out_size, void* d_ws, size_t ws_size,
                              hipStream_t stream) {
    const float* x   = (const float*)d_in[0];
    const float* Wx  = (const float*)d_in[1];
    const float* Wh  = (const float*)d_in[2];
    const float* Wo  = (const float*)d_in[3];
    const float* Wc1 = (const float*)d_in[4];
    const float* Wc2 = (const float*)d_in[5];
    float* out = (float*)d_out;
    float* feats = (float*)d_ws;              // B*T*6 fp32 = 3.1 MB

    k_prep<<<(BB * TT + 255) / 256, 256, 0, stream>>>(x, Wc1, Wc2, feats, out);
    k_gru<<<BB, 768, 0, stream>>>(feats, Wx, Wh, Wo, out);
}

// Round 2
// 12364.771 us; speedup vs baseline: 4.0667x; 4.0667x over previous
//
#include <hip/hip_runtime.h>
#include <math.h>

#define HH 256
#define FIN 6
#define TT 4096
#define BB 32
#define TH 0.05f

typedef _Float16 h2 __attribute__((ext_vector_type(2)));
struct H8 { h2 a, b, c, d; };   // 16 B = 8 halfs

__device__ __forceinline__ float hswish(float v) {
    float c = fminf(fmaxf(v + 3.0f, 0.0f), 6.0f);
    return v * c * (1.0f / 6.0f);
}
__device__ __forceinline__ float fexp2(float x) { return __builtin_amdgcn_exp2f(x); }
__device__ __forceinline__ float frcp(float x)  { return __builtin_amdgcn_rcpf(x); }
__device__ __forceinline__ float sigm(float x)  { return frcp(1.0f + fexp2(-1.44269504f * x)); }
__device__ __forceinline__ float tanhf_fast(float x) {
    float ax = fabsf(x);
    float e = fexp2(2.88539008f * ax);           // exp(2|x|)
    float t = 1.0f - 2.0f * frcp(e + 1.0f);      // tanh(|x|)
    return copysignf(t, x);
}

// Kernel 1: feats (B,T,6) into ws, conv skip path into d_out.
__global__ __launch_bounds__(256) void k_prep(
        const float* __restrict__ x, const float* __restrict__ Wc1,
        const float* __restrict__ Wc2, float* __restrict__ feats,
        float* __restrict__ out) {
    int idx = blockIdx.x * 256 + threadIdx.x;   // b*T + t
    if (idx >= BB * TT) return;
    int b = idx >> 12;
    int t = idx & (TT - 1);
    const float* xb = x + (size_t)b * TT * 2;
    float i0 = xb[t * 2 + 0], q0 = xb[t * 2 + 1];
    float ip = (t > 0) ? xb[(t - 1) * 2 + 0] : 0.0f;
    float qp = (t > 0) ? xb[(t - 1) * 2 + 1] : 0.0f;
    float amp2 = i0 * i0 + q0 * q0;
    float amp  = sqrtf(fmaxf(amp2, 1e-12f));
    float amp3 = amp * amp2;
    float* f = feats + (size_t)idx * 6;
    f[0] = i0; f[1] = q0; f[2] = amp; f[3] = amp3; f[4] = ip; f[5] = qp;

    float c1[3];
#pragma unroll
    for (int m = 0; m < 3; m++) {
        float acc = 0.0f;
#pragma unroll
        for (int k = 0; k < 3; k++) {
            int tt = t + (k - 1) * 16;
            if (tt >= 0 && tt < TT) {
                acc += Wc1[m * 6 + 0 * 3 + k] * xb[tt * 2 + 0];
                acc += Wc1[m * 6 + 1 * 3 + k] * xb[tt * 2 + 1];
            }
        }
        c1[m] = hswish(acc);
    }
#pragma unroll
    for (int o = 0; o < 2; o++) {
        float acc = Wc2[o * 3 + 0] * c1[0] + Wc2[o * 3 + 1] * c1[1] + Wc2[o * 3 + 2] * c1[2];
        out[(size_t)idx * 2 + o] = hswish(acc);
    }
}

// Kernel 2: delta-GRU, one block (1 CU) per batch, 256 threads.
// Thread j owns Wh rows {j, 256+j, 512+j} as packed fp16 in registers (384 VGPRs),
// plus all per-j recurrent state (h, hp, dm_r/z/n, dm_nh) -> 1 barrier/step.
__global__ __launch_bounds__(256, 1) void k_gru(
        const float* __restrict__ feats, const float* __restrict__ Wx,
        const float* __restrict__ Wh, const float* __restrict__ Wo,
        float* __restrict__ out) {
    __shared__ float s_out[TT * 2];                    // 32 KB output accumulator
    __shared__ __align__(16) _Float16 s_dhh[2][HH];    // 1 KB, double-buffered dh (fp16)
    __shared__ float s_feat[2][128 * FIN];             // 6 KB, double-buffered feat windows
    __shared__ float s_dx[2][FIN];

    const int tid = threadIdx.x;
    const int b = blockIdx.x;
    const float* fb = feats + (size_t)b * TT * FIN;

    for (int i = tid; i < TT * 2; i += 256) s_out[i] = 0.0f;

    // stage feats window 0 (steps 0..127) into buffer 0
#pragma unroll
    for (int k = 0; k < 3; k++) s_feat[0][tid + k * 256] = fb[tid + k * 256];

    // persistent weights: 3 rows of Wh as fp16 pairs
    h2 wr[128], wz[128], wn[128];
    {
        const float4* p0 = (const float4*)(Wh + (size_t)(0 * HH + tid) * HH);
        const float4* p1 = (const float4*)(Wh + (size_t)(1 * HH + tid) * HH);
        const float4* p2 = (const float4*)(Wh + (size_t)(2 * HH + tid) * HH);
#pragma unroll
        for (int c = 0; c < 64; c++) {
            float4 v0 = p0[c], v1 = p1[c], v2 = p2[c];
            wr[2 * c]     = h2{(_Float16)v0.x, (_Float16)v0.y};
            wr[2 * c + 1] = h2{(_Float16)v0.z, (_Float16)v0.w};
            wz[2 * c]     = h2{(_Float16)v1.x, (_Float16)v1.y};
            wz[2 * c + 1] = h2{(_Float16)v1.z, (_Float16)v1.w};
            wn[2 * c]     = h2{(_Float16)v2.x, (_Float16)v2.y};
            wn[2 * c + 1] = h2{(_Float16)v2.z, (_Float16)v2.w};
        }
    }
    float wxr[FIN], wxz[FIN], wxn[FIN];
#pragma unroll
    for (int f = 0; f < FIN; f++) {
        wxr[f] = Wx[(size_t)(0 * HH + tid) * FIN + f];
        wxz[f] = Wx[(size_t)(1 * HH + tid) * FIN + f];
        wxn[f] = Wx[(size_t)(2 * HH + tid) * FIN + f];
    }
    const float wo0 = Wo[tid], wo1 = Wo[HH + tid];

    float h = 0.0f, hp = 0.0f, dmr = 0.0f, dmz = 0.0f, dmn = 0.0f, dmnh = 0.0f;
    float xp = 0.0f, curf = 0.0f;
    if (tid < FIN) curf = fb[tid];

    __syncthreads();

    for (int t = 0; t < TT; t++) {
        const int tb = t & 1;

        // stage NEXT feats window mid-way through the current one (WAR-safe)
        if ((t & 127) == 64 && t + 64 < TT) {
            const int w = (t >> 7) + 1;       // window starting at step w*128 = t+64
#pragma unroll
            for (int k = 0; k < 3; k++)
                s_feat[w & 1][tid + k * 256] = fb[(size_t)w * 128 * FIN + tid + k * 256];
        }

        // ---- phase A (pre-barrier): thresholded deltas ----
        {
            float dh = h - hp;
            bool keep = fabsf(dh) >= TH;
            s_dhh[tb][tid] = (_Float16)(keep ? dh : 0.0f);
            if (keep) hp = h;
        }
        if (tid < FIN) {
            float dx = curf - xp;
            bool keep = fabsf(dx) >= TH;
            s_dx[tb][tid] = keep ? dx : 0.0f;
            if (keep) xp = curf;
        }
        __syncthreads();

        // ---- phase B: mac_x + register-resident fp16 dot over broadcast dh ----
        float mxr = dmr, mxz = dmz, mxn = dmn;
#pragma unroll
        for (int f = 0; f < FIN; f++) {
            float d = s_dx[tb][f];
            mxr = fmaf(d, wxr[f], mxr);
            mxz = fmaf(d, wxz[f], mxz);
            mxn = fmaf(d, wxn[f], mxn);
        }
        float ar0 = 0, ar1 = 0, az0 = 0, az1 = 0, an0 = 0, an1 = 0;
        const H8* dp = (const H8*)s_dhh[tb];
#pragma unroll
        for (int c = 0; c < 32; c++) {
            H8 d = dp[c];
            ar0 = __builtin_amdgcn_fdot2(d.a, wr[4 * c + 0], ar0, false);
            az0 = __builtin_amdgcn_fdot2(d.a, wz[4 * c + 0], az0, false);
            an0 = __builtin_amdgcn_fdot2(d.a, wn[4 * c + 0], an0, false);
            ar1 = __builtin_amdgcn_fdot2(d.b, wr[4 * c + 1], ar1, false);
            az1 = __builtin_amdgcn_fdot2(d.b, wz[4 * c + 1], az1, false);
            an1 = __builtin_amdgcn_fdot2(d.b, wn[4 * c + 1], an1, false);
            ar0 = __builtin_amdgcn_fdot2(d.c, wr[4 * c + 2], ar0, false);
            az0 = __builtin_amdgcn_fdot2(d.c, wz[4 * c + 2], az0, false);
            an0 = __builtin_amdgcn_fdot2(d.c, wn[4 * c + 2], an0, false);
            ar1 = __builtin_amdgcn_fdot2(d.d, wr[4 * c + 3], ar1, false);
            az1 = __builtin_amdgcn_fdot2(d.d, wz[4 * c + 3], az1, false);
            an1 = __builtin_amdgcn_fdot2(d.d, wn[4 * c + 3], an1, false);
        }
        dmr = mxr + (ar0 + ar1);
        dmz = mxz + (az0 + az1);
        dmn = mxn;
        dmnh += (an0 + an1);

        // ---- phase C (all thread-local): gates + h update ----
        {
            float r = sigm(dmr);
            float z = sigm(dmz);
            float nn = tanhf_fast(dmn + r * dmnh);
            h = (1.0f - z) * nn + z * h;
        }

        // ---- output: h @ Wo.T, wave shfl-reduce + LDS atomic accumulate ----
        {
            float p0 = h * wo0, p1 = h * wo1;
#pragma unroll
            for (int s = 32; s >= 1; s >>= 1) {
                p0 += __shfl_down(p0, s, 64);
                p1 += __shfl_down(p1, s, 64);
            }
            if ((tid & 63) == 0) {
                atomicAdd(&s_out[2 * t + 0], p0);
                atomicAdd(&s_out[2 * t + 1], p1);
            }
        }

        // prefetch next step's feature from LDS window (no global access in loop)
        if (tid < FIN && t + 1 < TT) {
            const int tn = t + 1;
            curf = s_feat[(tn >> 7) & 1][(tn & 127) * FIN + tid];
        }
    }

    __syncthreads();
    const size_t outbase = (size_t)b * TT * 2;
    for (int i = tid; i < TT * 2; i += 256) out[outbase + i] += s_out[i];
}

extern "C" void kernel_launch(void* const* d_in, const int* in_sizes, int n_in,
                              void* d_out, int out_size, void* d_ws, size_t ws_size,
                              hipStream_t stream) {
    const float* x   = (const float*)d_in[0];
    const float* Wx  = (const float*)d_in[1];
    const float* Wh  = (const float*)d_in[2];
    const float* Wo  = (const float*)d_in[3];
    const float* Wc1 = (const float*)d_in[4];
    const float* Wc2 = (const float*)d_in[5];
    float* out = (float*)d_out;
    float* feats = (float*)d_ws;              // B*T*6 fp32 = 3.1 MB

    k_prep<<<(BB * TT + 255) / 256, 256, 0, stream>>>(x, Wc1, Wc2, feats, out);
    k_gru<<<BB, 256, 0, stream>>>(feats, Wx, Wh, Wo, out);
}

// Round 3
// 5216.303 us; speedup vs baseline: 9.6398x; 2.3704x over previous
//
#include <hip/hip_runtime.h>
#include <math.h>

#define HH 256
#define FIN 6
#define TT 4096
#define BB 32
#define TH 0.05f

typedef _Float16 h2 __attribute__((ext_vector_type(2)));
struct H8 { h2 a, b, c, d; };   // 16 B = 8 halfs

__device__ __forceinline__ float hswish(float v) {
    float c = fminf(fmaxf(v + 3.0f, 0.0f), 6.0f);
    return v * c * (1.0f / 6.0f);
}
__device__ __forceinline__ float fexp2(float x) { return __builtin_amdgcn_exp2f(x); }
__device__ __forceinline__ float frcp(float x)  { return __builtin_amdgcn_rcpf(x); }
__device__ __forceinline__ float sigm(float x)  { return frcp(1.0f + fexp2(-1.44269504f * x)); }
__device__ __forceinline__ float tanhf_fast(float x) {
    float ax = fabsf(x);
    float e = fexp2(2.88539008f * ax);           // exp(2|x|)
    float t = 1.0f - 2.0f * frcp(e + 1.0f);      // tanh(|x|)
    return copysignf(t, x);
}

// Kernel 1: feats (B,T,6) into ws, conv skip path into d_out.
__global__ __launch_bounds__(256) void k_prep(
        const float* __restrict__ x, const float* __restrict__ Wc1,
        const float* __restrict__ Wc2, float* __restrict__ feats,
        float* __restrict__ out) {
    int idx = blockIdx.x * 256 + threadIdx.x;   // b*T + t
    if (idx >= BB * TT) return;
    int b = idx >> 12;
    int t = idx & (TT - 1);
    const float* xb = x + (size_t)b * TT * 2;
    float i0 = xb[t * 2 + 0], q0 = xb[t * 2 + 1];
    float ip = (t > 0) ? xb[(t - 1) * 2 + 0] : 0.0f;
    float qp = (t > 0) ? xb[(t - 1) * 2 + 1] : 0.0f;
    float amp2 = i0 * i0 + q0 * q0;
    float amp  = sqrtf(fmaxf(amp2, 1e-12f));
    float amp3 = amp * amp2;
    float* f = feats + (size_t)idx * 6;
    f[0] = i0; f[1] = q0; f[2] = amp; f[3] = amp3; f[4] = ip; f[5] = qp;

    float c1[3];
#pragma unroll
    for (int m = 0; m < 3; m++) {
        float acc = 0.0f;
#pragma unroll
        for (int k = 0; k < 3; k++) {
            int tt = t + (k - 1) * 16;
            if (tt >= 0 && tt < TT) {
                acc += Wc1[m * 6 + 0 * 3 + k] * xb[tt * 2 + 0];
                acc += Wc1[m * 6 + 1 * 3 + k] * xb[tt * 2 + 1];
            }
        }
        c1[m] = hswish(acc);
    }
#pragma unroll
    for (int o = 0; o < 2; o++) {
        float acc = Wc2[o * 3 + 0] * c1[0] + Wc2[o * 3 + 1] * c1[1] + Wc2[o * 3 + 2] * c1[2];
        out[(size_t)idx * 2 + o] = hswish(acc);
    }
}

// Kernel 2: delta-GRU, one block (1 CU) per batch, 512 threads (8 waves).
// K-split layout: wave w, lanes (l, l+32) both own row w*32+(l&31) of all 3
// gates, each holding HALF of the K=256 weights as fp16 (64 h2 x 3 = 192 VGPR).
// Partials combine via shfl_xor(32); all recurrent state is redundantly
// maintained in both halves (identical arithmetic) -> 1 barrier/step.
__global__ __launch_bounds__(512, 2) void k_gru(
        const float* __restrict__ feats, const float* __restrict__ Wx,
        const float* __restrict__ Wh, const float* __restrict__ Wo,
        float* __restrict__ out) {
    __shared__ float s_out[TT * 2];                    // 32 KB output accumulator
    __shared__ __align__(16) _Float16 s_dhh[2][HH];    // 1 KB, double-buffered dh (fp16)
    __shared__ __align__(16) float s_dx[2][8];         // dx (fp32), padded to 8
    __shared__ float s_feat[2][128 * FIN];             // 6 KB, double-buffered feat windows

    const int tid  = threadIdx.x;
    const int wv   = tid >> 6;          // wave 0..7
    const int lane = tid & 63;
    const int half = lane >> 5;         // K-half 0/1
    const int row  = wv * 32 + (lane & 31);   // 0..255
    const int b    = blockIdx.x;
    const float* fb = feats + (size_t)b * TT * FIN;

    for (int i = tid; i < TT * 2; i += 512) s_out[i] = 0.0f;
    for (int i = tid; i < 128 * FIN; i += 512) s_feat[0][i] = fb[i];

    // persistent weights: 3 gate-rows, this thread's K-half, packed fp16
    h2 wr[64], wz[64], wn[64];
    {
        const int k0 = half * 128;
        const float4* p0 = (const float4*)(Wh + (size_t)(0 * HH + row) * HH + k0);
        const float4* p1 = (const float4*)(Wh + (size_t)(1 * HH + row) * HH + k0);
        const float4* p2 = (const float4*)(Wh + (size_t)(2 * HH + row) * HH + k0);
#pragma unroll
        for (int c = 0; c < 32; c++) {
            float4 v0 = p0[c], v1 = p1[c], v2 = p2[c];
            wr[2 * c]     = h2{(_Float16)v0.x, (_Float16)v0.y};
            wr[2 * c + 1] = h2{(_Float16)v0.z, (_Float16)v0.w};
            wz[2 * c]     = h2{(_Float16)v1.x, (_Float16)v1.y};
            wz[2 * c + 1] = h2{(_Float16)v1.z, (_Float16)v1.w};
            wn[2 * c]     = h2{(_Float16)v2.x, (_Float16)v2.y};
            wn[2 * c + 1] = h2{(_Float16)v2.z, (_Float16)v2.w};
        }
    }
    float wxr[FIN], wxz[FIN], wxn[FIN];
#pragma unroll
    for (int f = 0; f < FIN; f++) {
        wxr[f] = Wx[(size_t)(0 * HH + row) * FIN + f];
        wxz[f] = Wx[(size_t)(1 * HH + row) * FIN + f];
        wxn[f] = Wx[(size_t)(2 * HH + row) * FIN + f];
    }
    const float woc = Wo[half * HH + row];   // half 0 -> ch0 weights, half 1 -> ch1

    float h = 0.0f, hp = 0.0f, dmr = 0.0f, dmz = 0.0f, dmn = 0.0f, dmnh = 0.0f;
    float xp = 0.0f, curf = 0.0f;
    if (tid < FIN) curf = fb[tid];

    __syncthreads();

    for (int t = 0; t < TT; t++) {
        const int tb = t & 1;

        // stage NEXT feats window mid-way through the current one (WAR-safe)
        if ((t & 127) == 64 && t + 64 < TT) {
            const int w = (t >> 7) + 1;
            for (int i = tid; i < 128 * FIN; i += 512)
                s_feat[w & 1][i] = fb[(size_t)w * 128 * FIN + i];
        }

        // ---- phase A: thresholded deltas (redundant in both halves) ----
        {
            float dh = h - hp;
            bool keep = fabsf(dh) >= TH;
            if (half == 0) s_dhh[tb][row] = (_Float16)(keep ? dh : 0.0f);
            if (keep) hp = h;
        }
        if (tid < FIN) {
            float dx = curf - xp;
            bool keep = fabsf(dx) >= TH;
            s_dx[tb][tid] = keep ? dx : 0.0f;
            if (keep) xp = curf;
        }
        __syncthreads();

        // ---- phase B: mac_x (fp32) + half-K fp16 dot over broadcast dh ----
        float mxr = dmr, mxz = dmz, mxn = dmn;
        {
            const float4* dx4 = (const float4*)s_dx[tb];
            float4 da = dx4[0], db = dx4[1];
            mxr = fmaf(da.x, wxr[0], mxr); mxz = fmaf(da.x, wxz[0], mxz); mxn = fmaf(da.x, wxn[0], mxn);
            mxr = fmaf(da.y, wxr[1], mxr); mxz = fmaf(da.y, wxz[1], mxz); mxn = fmaf(da.y, wxn[1], mxn);
            mxr = fmaf(da.z, wxr[2], mxr); mxz = fmaf(da.z, wxz[2], mxz); mxn = fmaf(da.z, wxn[2], mxn);
            mxr = fmaf(da.w, wxr[3], mxr); mxz = fmaf(da.w, wxz[3], mxz); mxn = fmaf(da.w, wxn[3], mxn);
            mxr = fmaf(db.x, wxr[4], mxr); mxz = fmaf(db.x, wxz[4], mxz); mxn = fmaf(db.x, wxn[4], mxn);
            mxr = fmaf(db.y, wxr[5], mxr); mxz = fmaf(db.y, wxz[5], mxz); mxn = fmaf(db.y, wxn[5], mxn);
        }
        float ar = 0.0f, az = 0.0f, an = 0.0f;
        {
            const H8* dp = (const H8*)s_dhh[tb] + half * 16;
#pragma unroll
            for (int c = 0; c < 16; c++) {
                H8 d = dp[c];
                ar = __builtin_amdgcn_fdot2(d.a, wr[4 * c + 0], ar, false);
                az = __builtin_amdgcn_fdot2(d.a, wz[4 * c + 0], az, false);
                an = __builtin_amdgcn_fdot2(d.a, wn[4 * c + 0], an, false);
                ar = __builtin_amdgcn_fdot2(d.b, wr[4 * c + 1], ar, false);
                az = __builtin_amdgcn_fdot2(d.b, wz[4 * c + 1], az, false);
                an = __builtin_amdgcn_fdot2(d.b, wn[4 * c + 1], an, false);
                ar = __builtin_amdgcn_fdot2(d.c, wr[4 * c + 2], ar, false);
                az = __builtin_amdgcn_fdot2(d.c, wz[4 * c + 2], az, false);
                an = __builtin_amdgcn_fdot2(d.c, wn[4 * c + 2], an, false);
                ar = __builtin_amdgcn_fdot2(d.d, wr[4 * c + 3], ar, false);
                az = __builtin_amdgcn_fdot2(d.d, wz[4 * c + 3], az, false);
                an = __builtin_amdgcn_fdot2(d.d, wn[4 * c + 3], an, false);
            }
        }
        // combine K-halves (both sides end with identical full sums)
        ar += __shfl_xor(ar, 32, 64);
        az += __shfl_xor(az, 32, 64);
        an += __shfl_xor(an, 32, 64);

        dmr = mxr + ar;
        dmz = mxz + az;
        dmn = mxn;
        dmnh += an;

        // ---- phase C (thread-local, redundant in both halves) ----
        {
            float r = sigm(dmr);
            float z = sigm(dmz);
            float nn = tanhf_fast(dmn + r * dmnh);
            h = (1.0f - z) * nn + z * h;
        }

        // ---- output: half 0 -> channel 0, half 1 -> channel 1 ----
        {
            float p = h * woc;
            p += __shfl_xor(p, 16, 64);
            p += __shfl_xor(p, 8, 64);
            p += __shfl_xor(p, 4, 64);
            p += __shfl_xor(p, 2, 64);
            p += __shfl_xor(p, 1, 64);
            if ((lane & 31) == 0) atomicAdd(&s_out[2 * t + half], p);
        }

        // prefetch next step's feature from LDS window
        if (tid < FIN && t + 1 < TT) {
            const int tn = t + 1;
            curf = s_feat[(tn >> 7) & 1][(tn & 127) * FIN + tid];
        }
    }

    __syncthreads();
    const size_t outbase = (size_t)b * TT * 2;
    for (int i = tid; i < TT * 2; i += 512) out[outbase + i] += s_out[i];
}

extern "C" void kernel_launch(void* const* d_in, const int* in_sizes, int n_in,
                              void* d_out, int out_size, void* d_ws, size_t ws_size,
                              hipStream_t stream) {
    const float* x   = (const float*)d_in[0];
    const float* Wx  = (const float*)d_in[1];
    const float* Wh  = (const float*)d_in[2];
    const float* Wo  = (const float*)d_in[3];
    const float* Wc1 = (const float*)d_in[4];
    const float* Wc2 = (const float*)d_in[5];
    float* out = (float*)d_out;
    float* feats = (float*)d_ws;              // B*T*6 fp32 = 3.1 MB

    k_prep<<<(BB * TT + 255) / 256, 256, 0, stream>>>(x, Wc1, Wc2, feats, out);
    k_gru<<<BB, 512, 0, stream>>>(feats, Wx, Wh, Wo, out);
}